// Round 9
// baseline (257.262 us; speedup 1.0000x reference)
//
#include <hip/hip_runtime.h>
#include <hip/hip_fp16.h>

#define D 128
#define LN_EPS 1e-5f

// Dtypes (R0-R7 forensics): x,W,b,gamma,beta fp32; edge_index int32; out fp32.
// R8 baseline PASSED (absmax 0.0156, fused 80us, FETCH 48MB, occ 25%).
// R9: x->fp16 (2.56MB, fits 4MiB XCD L2), W fp16 in LDS (32KB -> 32 waves/CU),
//     (src,wt) packed u32 CSR (no dinv gather, 1 shfl/edge).

static __device__ __forceinline__ float h2f(unsigned short h) {
    return __half2float(__builtin_bit_cast(__half, h));
}
static __device__ __forceinline__ unsigned short f2h(float f) {
    return __builtin_bit_cast(unsigned short, __float2half_rn(f));
}

// ================= fast path (ws >= ~5.3 MB) =================

// ---- P1: convert x (float2 pairs) -> packed fp16 words; count in-degrees ----
__global__ void prep_kernel(const float* __restrict__ x, unsigned int* __restrict__ xh,
                            const int* __restrict__ dst, int* __restrict__ deg,
                            int NH, int E) {
    int stride = gridDim.x * blockDim.x;
    int limit = max(NH, E);
    for (int i = blockIdx.x * blockDim.x + threadIdx.x; i < limit; i += stride) {
        if (i < NH) {
            float2 v = ((const float2*)x)[i];
            xh[i] = (unsigned int)f2h(v.x) | ((unsigned int)f2h(v.y) << 16);
        }
        if (i < E) atomicAdd(&deg[dst[i]], 1);
    }
}

// ---- K2: exclusive scan of deg -> rowptr/fill, dinv = rsqrt(deg+1) ----
__global__ __launch_bounds__(1024) void scan_kernel(const int* __restrict__ deg,
                                                    int* __restrict__ rowptr,
                                                    int* __restrict__ fill,
                                                    float* __restrict__ dinv, int N) {
    __shared__ int s_wsum[16];
    __shared__ int s_woff[16];
    __shared__ int s_carry;
    int t = threadIdx.x;
    int lane = t & 63, w = t >> 6;
    if (t == 0) s_carry = 0;
    __syncthreads();
    for (int base = 0; base < N; base += 1024) {
        int i = base + t;
        int v = (i < N) ? deg[i] : 0;
        int incl = v;
        #pragma unroll
        for (int off = 1; off < 64; off <<= 1) {
            int y = __shfl_up(incl, off);
            if (lane >= off) incl += y;
        }
        if (lane == 63) s_wsum[w] = incl;
        __syncthreads();
        if (t == 0) {
            int run = s_carry;
            #pragma unroll
            for (int k = 0; k < 16; k++) { s_woff[k] = run; run += s_wsum[k]; }
            s_carry = run;
        }
        __syncthreads();
        if (i < N) {
            int rp = s_woff[w] + (incl - v);
            rowptr[i] = rp;
            fill[i] = rp;
            dinv[i] = rsqrtf((float)(v + 1));  // +1 self-loop
        }
    }
    if (t == 0) rowptr[N] = s_carry;
}

// ---- K3: CSR fill with packed (src u16 | wt fp16 << 16) ----
__global__ void fill2_kernel(const int* __restrict__ src, const int* __restrict__ dst,
                             const float* __restrict__ dinv,
                             int* __restrict__ fill, unsigned int* __restrict__ csr32, int E) {
    int e = blockIdx.x * blockDim.x + threadIdx.x;
    if (e < E) {
        int s = src[e], d = dst[e];
        int pos = atomicAdd(&fill[d], 1);
        float wt = dinv[s] * dinv[d];
        csr32[pos] = (unsigned int)s | ((unsigned int)f2h(wt) << 16);
    }
}

// ---- K4: fused aggregate -> linear -> LayerNorm. One wave/node, 8 waves/block,
// W as packed fp16 in LDS (32 KB -> 4 blocks/CU -> 32 waves/CU).
__global__ __launch_bounds__(512) void fused_fp16(const unsigned int* __restrict__ xh,
                                                  const float* __restrict__ W,
                                                  const int* __restrict__ rowptr,
                                                  const unsigned int* __restrict__ csr32,
                                                  const float* __restrict__ dinv,
                                                  const float* __restrict__ bias,
                                                  const float* __restrict__ gamma,
                                                  const float* __restrict__ beta,
                                                  float* __restrict__ out, int N) {
    __shared__ unsigned int sW2[D * (D / 2)];   // 32 KB: row k, col-pair c
    {
        const float2* Wv = (const float2*)W;    // linear float2 idx == k*64+c
        #pragma unroll
        for (int i = 0; i < (D * D / 2) / 512; i++) {
            int idx = threadIdx.x + i * 512;
            float2 wv = Wv[idx];
            sW2[idx] = (unsigned int)f2h(wv.x) | ((unsigned int)f2h(wv.y) << 16);
        }
    }
    __syncthreads();

    int w = threadIdx.x >> 6, lane = threadIdx.x & 63;
    int node = blockIdx.x * 8 + w;
    if (node >= N) return;
    float dn = dinv[node];

    // self-loop: dinv^2 * x[n]
    unsigned int xv = xh[node * 64 + lane];
    float a0 = h2f((unsigned short)xv) * dn * dn;
    float a1 = h2f((unsigned short)(xv >> 16)) * dn * dn;

    // neighbor aggregation; one packed shfl broadcast per edge
    int start = rowptr[node], end = rowptr[node + 1];
    int base = start;
    for (; base + 64 <= end; base += 64) {
        unsigned int p = csr32[base + lane];
        #pragma unroll 8
        for (int k = 0; k < 64; k++) {
            unsigned int pk = __shfl(p, k);
            int sk = pk & 0xffffu;
            float wk = h2f((unsigned short)(pk >> 16));
            unsigned int hv = xh[sk * 64 + lane];
            a0 += h2f((unsigned short)hv) * wk;
            a1 += h2f((unsigned short)(hv >> 16)) * wk;
        }
    }
    int rem = end - base;
    if (rem > 0) {
        unsigned int p = (lane < rem) ? csr32[base + lane] : 0;
        for (int k = 0; k < rem; k++) {
            unsigned int pk = __shfl(p, k);
            int sk = pk & 0xffffu;
            float wk = h2f((unsigned short)(pk >> 16));
            unsigned int hv = xh[sk * 64 + lane];
            a0 += h2f((unsigned short)hv) * wk;
            a1 += h2f((unsigned short)(hv >> 16)) * wk;
        }
    }

    // linear: y[n] = sum_k agg[k]*W[k][n] + b[n]; lane owns cols 2*lane, 2*lane+1
    int c0 = lane * 2;
    float y0 = bias[c0], y1 = bias[c0 + 1];
    #pragma unroll 8
    for (int k = 0; k < 64; k++) {
        float g0 = __shfl(a0, k);                      // agg[2k]
        float g1 = __shfl(a1, k);                      // agg[2k+1]
        unsigned int w0 = sW2[(2 * k) * 64 + lane];    // W[2k][c0], W[2k][c0+1]
        unsigned int w1 = sW2[(2 * k + 1) * 64 + lane];
        y0 += g0 * h2f((unsigned short)w0) + g1 * h2f((unsigned short)w1);
        y1 += g0 * h2f((unsigned short)(w0 >> 16)) + g1 * h2f((unsigned short)(w1 >> 16));
    }

    // LayerNorm over 128 features (2 per lane)
    float sum = y0 + y1, sq = y0 * y0 + y1 * y1;
    #pragma unroll
    for (int off = 32; off > 0; off >>= 1) {
        sum += __shfl_xor(sum, off);
        sq  += __shfl_xor(sq, off);
    }
    float mean = sum * (1.0f / D);
    float var  = sq * (1.0f / D) - mean * mean;
    float inv  = rsqrtf(var + LN_EPS);
    float o0 = (y0 - mean) * inv * gamma[c0] + beta[c0];
    float o1 = (y1 - mean) * inv * gamma[c0 + 1] + beta[c0 + 1];
    *(float2*)(out + (size_t)node * D + c0) = make_float2(o0, o1);
}

// ================= fallback path (R8, proven) =================

__global__ void deg_kernel(const int* __restrict__ dst, int* __restrict__ deg, int E) {
    int e = blockIdx.x * blockDim.x + threadIdx.x;
    if (e < E) atomicAdd(&deg[dst[e]], 1);
}

__global__ void fill_kernel(const int* __restrict__ src, const int* __restrict__ dst,
                            int* __restrict__ fill, unsigned short* __restrict__ csr, int E) {
    int e = blockIdx.x * blockDim.x + threadIdx.x;
    if (e < E) {
        int pos = atomicAdd(&fill[dst[e]], 1);
        csr[pos] = (unsigned short)src[e];
    }
}

__global__ __launch_bounds__(512) void fused_fp32(const float* __restrict__ x,
                                                  const float* __restrict__ W,
                                                  const int* __restrict__ rowptr,
                                                  const unsigned short* __restrict__ csr,
                                                  const float* __restrict__ dinv,
                                                  const float* __restrict__ bias,
                                                  const float* __restrict__ gamma,
                                                  const float* __restrict__ beta,
                                                  float* __restrict__ out, int N) {
    __shared__ float sW[D * D];
    {
        const float4* Wv = (const float4*)W;
        float4* sWv = (float4*)sW;
        #pragma unroll
        for (int i = 0; i < (D * D / 4) / 512; i++)
            sWv[threadIdx.x + i * 512] = Wv[threadIdx.x + i * 512];
    }
    __syncthreads();
    int w = threadIdx.x >> 6, lane = threadIdx.x & 63;
    int node = blockIdx.x * 8 + w;
    if (node >= N) return;
    float dn = dinv[node];
    int c0 = lane * 2;
    float2 xv = *(const float2*)(x + (size_t)node * D + c0);
    float a0 = xv.x * dn * dn, a1 = xv.y * dn * dn;
    int start = rowptr[node], end = rowptr[node + 1];
    int base = start;
    for (; base + 64 <= end; base += 64) {
        int s = csr[base + lane];
        float wt = dinv[s] * dn;
        #pragma unroll 8
        for (int k = 0; k < 64; k++) {
            int sk = __shfl(s, k);
            float wk = __shfl(wt, k);
            float2 xs = *(const float2*)(x + (size_t)sk * D + c0);
            a0 += xs.x * wk; a1 += xs.y * wk;
        }
    }
    int rem = end - base;
    if (rem > 0) {
        int s = 0; float wt = 0.f;
        if (lane < rem) { s = csr[base + lane]; wt = dinv[s] * dn; }
        for (int k = 0; k < rem; k++) {
            int sk = __shfl(s, k);
            float wk = __shfl(wt, k);
            float2 xs = *(const float2*)(x + (size_t)sk * D + c0);
            a0 += xs.x * wk; a1 += xs.y * wk;
        }
    }
    float y0 = bias[c0], y1 = bias[c0 + 1];
    #pragma unroll 8
    for (int k = 0; k < 64; k++) {
        float g0 = __shfl(a0, k);
        float g1 = __shfl(a1, k);
        float2 w0 = *(const float2*)(sW + (2 * k) * D + c0);
        float2 w1 = *(const float2*)(sW + (2 * k + 1) * D + c0);
        y0 += g0 * w0.x + g1 * w1.x;
        y1 += g0 * w0.y + g1 * w1.y;
    }
    float sum = y0 + y1, sq = y0 * y0 + y1 * y1;
    #pragma unroll
    for (int off = 32; off > 0; off >>= 1) {
        sum += __shfl_xor(sum, off);
        sq  += __shfl_xor(sq, off);
    }
    float mean = sum * (1.0f / D);
    float var  = sq * (1.0f / D) - mean * mean;
    float inv  = rsqrtf(var + LN_EPS);
    float o0 = (y0 - mean) * inv * gamma[c0] + beta[c0];
    float o1 = (y1 - mean) * inv * gamma[c0 + 1] + beta[c0 + 1];
    *(float2*)(out + (size_t)node * D + c0) = make_float2(o0, o1);
}

extern "C" void kernel_launch(void* const* d_in, const int* in_sizes, int n_in,
                              void* d_out, int out_size, void* d_ws, size_t ws_size,
                              hipStream_t stream) {
    const float* x     = (const float*)d_in[0];
    const int*   ei    = (const int*)d_in[1];
    const float* W     = (const float*)d_in[2];
    const float* bias  = (const float*)d_in[3];
    const float* gamma = (const float*)d_in[4];
    const float* beta  = (const float*)d_in[5];
    float*       out   = (float*)d_out;

    int N = in_sizes[0] / D;
    int E = in_sizes[1] / 2;
    const int* src = ei;
    const int* dst = ei + E;

    char* ws = (char*)d_ws;
    size_t off = 0;
    auto carve = [&](size_t bytes) { size_t p = off; off = (off + bytes + 15) & ~15UL; return (void*)(ws + p); };
    int*   deg    = (int*)  carve((size_t)N * 4);
    int*   rowptr = (int*)  carve((size_t)(N + 1) * 4);
    int*   fill   = (int*)  carve((size_t)N * 4);
    float* dinv   = (float*)carve((size_t)N * 4);
    size_t aux_end = off;

    // fast-path extra: csr32 (4E) + xh (2*N*D)
    size_t need_fast = aux_end + ((size_t)E * 4 + 16) + ((size_t)N * D * 2 + 16);
    bool fast = (ws_size >= need_fast);

    hipMemsetAsync(deg, 0, (size_t)N * 4, stream);

    if (fast) {
        unsigned int* csr32 = (unsigned int*)carve((size_t)E * 4);
        unsigned int* xh    = (unsigned int*)carve((size_t)N * D / 2 * 4);
        int NH = N * (D / 2);
        int limit = max(NH, E);
        prep_kernel<<<(limit + 255) / 256, 256, 0, stream>>>(x, xh, dst, deg, NH, E);
        scan_kernel<<<1, 1024, 0, stream>>>(deg, rowptr, fill, dinv, N);
        fill2_kernel<<<(E + 255) / 256, 256, 0, stream>>>(src, dst, dinv, fill, csr32, E);
        fused_fp16<<<(N + 7) / 8, 512, 0, stream>>>(xh, W, rowptr, csr32, dinv, bias, gamma, beta, out, N);
    } else {
        unsigned short* csr = (unsigned short*)carve((size_t)E * 2);
        deg_kernel<<<(E + 255) / 256, 256, 0, stream>>>(dst, deg, E);
        scan_kernel<<<1, 1024, 0, stream>>>(deg, rowptr, fill, dinv, N);
        fill_kernel<<<(E + 255) / 256, 256, 0, stream>>>(src, dst, fill, csr, E);
        fused_fp32<<<(N + 7) / 8, 512, 0, stream>>>(x, W, rowptr, csr, dinv, bias, gamma, beta, out, N);
    }
}

// Round 10
// 177.661 us; speedup vs baseline: 1.4481x; 1.4481x over previous
//
#include <hip/hip_runtime.h>
#include <hip/hip_fp16.h>

#define D 128
#define LN_EPS 1e-5f

// Dtypes (R0-R7 forensics): x,W,b,gamma,beta fp32; edge_index int32; out fp32.
// R8: 234us (fused_fp32 80us top). R9: 257us — fill2 (global atomic-return +
// 4B scattered stores, 35MB writeback) = 106us top; fused_fp16 < 105 (helped).
// R10: atomic-free CSR build via chunked LDS-histogram counting sort + 2B csr.

static __device__ __forceinline__ float h2f(unsigned short h) {
    return __half2float(__builtin_bit_cast(__half, h));
}
static __device__ __forceinline__ unsigned short f2h(float f) {
    return __builtin_bit_cast(unsigned short, __float2half_rn(f));
}

// ---- H: per-chunk LDS histogram of dst; also converts x -> packed fp16 ----
__global__ __launch_bounds__(1024) void hist_kernel(const int* __restrict__ dst,
                                                    int* __restrict__ ghist,
                                                    const float* __restrict__ x,
                                                    unsigned int* __restrict__ xh,
                                                    int N, int E, int Ec, int NH) {
    extern __shared__ int hist[];          // N ints (40 KB)
    int c = blockIdx.x;
    for (int i = threadIdx.x; i < N; i += blockDim.x) hist[i] = 0;
    // x convert, grid-strided across all H blocks
    int gs = gridDim.x * blockDim.x;
    for (int i = blockIdx.x * blockDim.x + threadIdx.x; i < NH; i += gs) {
        float2 v = ((const float2*)x)[i];
        xh[i] = (unsigned int)f2h(v.x) | ((unsigned int)f2h(v.y) << 16);
    }
    __syncthreads();
    int lo = c * Ec, hi = min(lo + Ec, E);
    for (int i = lo + threadIdx.x; i < hi; i += blockDim.x)
        atomicAdd(&hist[dst[i]], 1);       // LDS atomic: cheap, no coherence
    __syncthreads();
    for (int i = threadIdx.x; i < N; i += blockDim.x) ghist[c * N + i] = hist[i];
}

// ---- S2: per-node exclusive scan over chunks (in place) -> deg ----
__global__ void chunkoff_kernel(int* __restrict__ ghist, int* __restrict__ deg,
                                int N, int C) {
    int n = blockIdx.x * blockDim.x + threadIdx.x;
    if (n < N) {
        int run = 0;
        for (int c = 0; c < C; c++) {      // coalesced across n for each c
            int t = ghist[c * N + n];
            ghist[c * N + n] = run;
            run += t;
        }
        deg[n] = run;
    }
}

// ---- scan: exclusive scan of deg -> rowptr (+fill for fallback), dinv ----
__global__ __launch_bounds__(1024) void scan_kernel(const int* __restrict__ deg,
                                                    int* __restrict__ rowptr,
                                                    int* __restrict__ fill,
                                                    float* __restrict__ dinv, int N) {
    __shared__ int s_wsum[16];
    __shared__ int s_woff[16];
    __shared__ int s_carry;
    int t = threadIdx.x;
    int lane = t & 63, w = t >> 6;
    if (t == 0) s_carry = 0;
    __syncthreads();
    for (int base = 0; base < N; base += 1024) {
        int i = base + t;
        int v = (i < N) ? deg[i] : 0;
        int incl = v;
        #pragma unroll
        for (int off = 1; off < 64; off <<= 1) {
            int y = __shfl_up(incl, off);
            if (lane >= off) incl += y;
        }
        if (lane == 63) s_wsum[w] = incl;
        __syncthreads();
        if (t == 0) {
            int run = s_carry;
            #pragma unroll
            for (int k = 0; k < 16; k++) { s_woff[k] = run; run += s_wsum[k]; }
            s_carry = run;
        }
        __syncthreads();
        if (i < N) {
            int rp = s_woff[w] + (incl - v);
            rowptr[i] = rp;
            fill[i] = rp;
            dinv[i] = rsqrtf((float)(v + 1));  // +1 self-loop
        }
    }
    if (t == 0) rowptr[N] = s_carry;
}

// ---- W: per-chunk scatter with LDS cursors; 2B stores, zero global atomics ----
__global__ __launch_bounds__(1024) void scatter_kernel(const int* __restrict__ src,
                                                       const int* __restrict__ dst,
                                                       const int* __restrict__ rowptr,
                                                       const int* __restrict__ goff,
                                                       unsigned short* __restrict__ csr,
                                                       int N, int E, int Ec) {
    extern __shared__ int cnt[];           // N ints
    int c = blockIdx.x;
    for (int i = threadIdx.x; i < N; i += blockDim.x)
        cnt[i] = rowptr[i] + goff[c * N + i];
    __syncthreads();
    int lo = c * Ec, hi = min(lo + Ec, E);
    for (int i = lo + threadIdx.x; i < hi; i += blockDim.x) {
        int d = dst[i];
        int pos = atomicAdd(&cnt[d], 1);   // LDS atomic-return: ~zero contention
        csr[pos] = (unsigned short)src[i];
    }
}

// ---- fused: aggregate (fp16 x, fp32 acc) -> linear (fp16 W in LDS) -> LN ----
__global__ __launch_bounds__(512) void fused_fp16(const unsigned int* __restrict__ xh,
                                                  const float* __restrict__ W,
                                                  const int* __restrict__ rowptr,
                                                  const unsigned short* __restrict__ csr,
                                                  const float* __restrict__ dinv,
                                                  const float* __restrict__ bias,
                                                  const float* __restrict__ gamma,
                                                  const float* __restrict__ beta,
                                                  float* __restrict__ out, int N) {
    __shared__ unsigned int sW2[D * (D / 2)];   // 32 KB -> 4 blocks/CU
    {
        const float2* Wv = (const float2*)W;
        #pragma unroll
        for (int i = 0; i < (D * D / 2) / 512; i++) {
            int idx = threadIdx.x + i * 512;
            float2 wv = Wv[idx];
            sW2[idx] = (unsigned int)f2h(wv.x) | ((unsigned int)f2h(wv.y) << 16);
        }
    }
    __syncthreads();

    int w = threadIdx.x >> 6, lane = threadIdx.x & 63;
    int node = blockIdx.x * 8 + w;
    if (node >= N) return;
    float dn = dinv[node];

    unsigned int xv = xh[node * 64 + lane];
    float a0 = h2f((unsigned short)xv) * dn * dn;
    float a1 = h2f((unsigned short)(xv >> 16)) * dn * dn;

    int start = rowptr[node], end = rowptr[node + 1];
    int base = start;
    for (; base + 64 <= end; base += 64) {
        int s = csr[base + lane];
        float wt = dinv[s] * dn;
        #pragma unroll 8
        for (int k = 0; k < 64; k++) {
            int sk = __shfl(s, k);
            float wk = __shfl(wt, k);
            unsigned int hv = xh[sk * 64 + lane];
            a0 += h2f((unsigned short)hv) * wk;
            a1 += h2f((unsigned short)(hv >> 16)) * wk;
        }
    }
    int rem = end - base;
    if (rem > 0) {
        int s = 0; float wt = 0.f;
        if (lane < rem) { s = csr[base + lane]; wt = dinv[s] * dn; }
        for (int k = 0; k < rem; k++) {
            int sk = __shfl(s, k);
            float wk = __shfl(wt, k);
            unsigned int hv = xh[sk * 64 + lane];
            a0 += h2f((unsigned short)hv) * wk;
            a1 += h2f((unsigned short)(hv >> 16)) * wk;
        }
    }

    int c0 = lane * 2;
    float y0 = bias[c0], y1 = bias[c0 + 1];
    #pragma unroll 8
    for (int k = 0; k < 64; k++) {
        float g0 = __shfl(a0, k);
        float g1 = __shfl(a1, k);
        unsigned int w0 = sW2[(2 * k) * 64 + lane];
        unsigned int w1 = sW2[(2 * k + 1) * 64 + lane];
        y0 += g0 * h2f((unsigned short)w0) + g1 * h2f((unsigned short)w1);
        y1 += g0 * h2f((unsigned short)(w0 >> 16)) + g1 * h2f((unsigned short)(w1 >> 16));
    }

    float sum = y0 + y1, sq = y0 * y0 + y1 * y1;
    #pragma unroll
    for (int off = 32; off > 0; off >>= 1) {
        sum += __shfl_xor(sum, off);
        sq  += __shfl_xor(sq, off);
    }
    float mean = sum * (1.0f / D);
    float var  = sq * (1.0f / D) - mean * mean;
    float inv  = rsqrtf(var + LN_EPS);
    float o0 = (y0 - mean) * inv * gamma[c0] + beta[c0];
    float o1 = (y1 - mean) * inv * gamma[c0 + 1] + beta[c0 + 1];
    *(float2*)(out + (size_t)node * D + c0) = make_float2(o0, o1);
}

// ================= fallback (R8, proven): used only if ws too small =========

__global__ void deg_kernel(const int* __restrict__ dst, int* __restrict__ deg, int E) {
    int e = blockIdx.x * blockDim.x + threadIdx.x;
    if (e < E) atomicAdd(&deg[dst[e]], 1);
}
__global__ void fill_kernel(const int* __restrict__ src, const int* __restrict__ dst,
                            int* __restrict__ fill, unsigned short* __restrict__ csr, int E) {
    int e = blockIdx.x * blockDim.x + threadIdx.x;
    if (e < E) {
        int pos = atomicAdd(&fill[dst[e]], 1);
        csr[pos] = (unsigned short)src[e];
    }
}
__global__ __launch_bounds__(512) void fused_fp32(const float* __restrict__ x,
                                                  const float* __restrict__ W,
                                                  const int* __restrict__ rowptr,
                                                  const unsigned short* __restrict__ csr,
                                                  const float* __restrict__ dinv,
                                                  const float* __restrict__ bias,
                                                  const float* __restrict__ gamma,
                                                  const float* __restrict__ beta,
                                                  float* __restrict__ out, int N) {
    __shared__ float sW[D * D];
    {
        const float4* Wv = (const float4*)W;
        float4* sWv = (float4*)sW;
        #pragma unroll
        for (int i = 0; i < (D * D / 4) / 512; i++)
            sWv[threadIdx.x + i * 512] = Wv[threadIdx.x + i * 512];
    }
    __syncthreads();
    int w = threadIdx.x >> 6, lane = threadIdx.x & 63;
    int node = blockIdx.x * 8 + w;
    if (node >= N) return;
    float dn = dinv[node];
    int c0 = lane * 2;
    float2 xv = *(const float2*)(x + (size_t)node * D + c0);
    float a0 = xv.x * dn * dn, a1 = xv.y * dn * dn;
    int start = rowptr[node], end = rowptr[node + 1];
    int base = start;
    for (; base + 64 <= end; base += 64) {
        int s = csr[base + lane];
        float wt = dinv[s] * dn;
        #pragma unroll 8
        for (int k = 0; k < 64; k++) {
            int sk = __shfl(s, k);
            float wk = __shfl(wt, k);
            float2 xs = *(const float2*)(x + (size_t)sk * D + c0);
            a0 += xs.x * wk; a1 += xs.y * wk;
        }
    }
    int rem = end - base;
    if (rem > 0) {
        int s = 0; float wt = 0.f;
        if (lane < rem) { s = csr[base + lane]; wt = dinv[s] * dn; }
        for (int k = 0; k < rem; k++) {
            int sk = __shfl(s, k);
            float wk = __shfl(wt, k);
            float2 xs = *(const float2*)(x + (size_t)sk * D + c0);
            a0 += xs.x * wk; a1 += xs.y * wk;
        }
    }
    float y0 = bias[c0], y1 = bias[c0 + 1];
    #pragma unroll 8
    for (int k = 0; k < 64; k++) {
        float g0 = __shfl(a0, k);
        float g1 = __shfl(a1, k);
        float2 w0 = *(const float2*)(sW + (2 * k) * D + c0);
        float2 w1 = *(const float2*)(sW + (2 * k + 1) * D + c0);
        y0 += g0 * w0.x + g1 * w1.x;
        y1 += g0 * w0.y + g1 * w1.y;
    }
    float sum = y0 + y1, sq = y0 * y0 + y1 * y1;
    #pragma unroll
    for (int off = 32; off > 0; off >>= 1) {
        sum += __shfl_xor(sum, off);
        sq  += __shfl_xor(sq, off);
    }
    float mean = sum * (1.0f / D);
    float var  = sq * (1.0f / D) - mean * mean;
    float inv  = rsqrtf(var + LN_EPS);
    float o0 = (y0 - mean) * inv * gamma[c0] + beta[c0];
    float o1 = (y1 - mean) * inv * gamma[c0 + 1] + beta[c0 + 1];
    *(float2*)(out + (size_t)node * D + c0) = make_float2(o0, o1);
}

extern "C" void kernel_launch(void* const* d_in, const int* in_sizes, int n_in,
                              void* d_out, int out_size, void* d_ws, size_t ws_size,
                              hipStream_t stream) {
    const float* x     = (const float*)d_in[0];
    const int*   ei    = (const int*)d_in[1];
    const float* W     = (const float*)d_in[2];
    const float* bias  = (const float*)d_in[3];
    const float* gamma = (const float*)d_in[4];
    const float* beta  = (const float*)d_in[5];
    float*       out   = (float*)d_out;

    int N = in_sizes[0] / D;
    int E = in_sizes[1] / 2;
    const int* src = ei;
    const int* dst = ei + E;

    char* ws = (char*)d_ws;
    size_t off = 0;
    auto carve = [&](size_t bytes) { size_t p = off; off = (off + bytes + 15) & ~15UL; return (void*)(ws + p); };
    int*            deg    = (int*)           carve((size_t)N * 4);
    int*            rowptr = (int*)           carve((size_t)(N + 1) * 4);
    int*            fill   = (int*)           carve((size_t)N * 4);
    float*          dinv   = (float*)         carve((size_t)N * 4);
    unsigned short* csr    = (unsigned short*)carve((size_t)E * 2);
    unsigned short* xhbuf  = (unsigned short*)carve((size_t)N * D * 2);
    size_t fixed_end = off;

    // chunks for the atomic-free counting sort: each needs N*4 bytes of ghist
    int C = 0;
    if (ws_size > fixed_end + 16) {
        size_t avail = ws_size - fixed_end - 16;
        size_t c64 = avail / ((size_t)N * 4);
        C = (int)((c64 > 128) ? 128 : c64);
    }

    if (C >= 8) {
        int* ghist = (int*)carve((size_t)C * N * 4);
        unsigned int* xh = (unsigned int*)xhbuf;
        int Ec = (E + C - 1) / C;
        int NH = N * (D / 2);
        size_t lds = (size_t)N * 4;
        hist_kernel<<<C, 1024, lds, stream>>>(dst, ghist, x, xh, N, E, Ec, NH);
        chunkoff_kernel<<<(N + 255) / 256, 256, 0, stream>>>(ghist, deg, N, C);
        scan_kernel<<<1, 1024, 0, stream>>>(deg, rowptr, fill, dinv, N);
        scatter_kernel<<<C, 1024, lds, stream>>>(src, dst, rowptr, ghist, csr, N, E, Ec);
        fused_fp16<<<(N + 7) / 8, 512, 0, stream>>>(xh, W, rowptr, csr, dinv, bias, gamma, beta, out, N);
    } else {
        hipMemsetAsync(deg, 0, (size_t)N * 4, stream);
        deg_kernel<<<(E + 255) / 256, 256, 0, stream>>>(dst, deg, E);
        scan_kernel<<<1, 1024, 0, stream>>>(deg, rowptr, fill, dinv, N);
        fill_kernel<<<(E + 255) / 256, 256, 0, stream>>>(src, dst, fill, csr, E);
        fused_fp32<<<(N + 7) / 8, 512, 0, stream>>>(x, W, rowptr, csr, dinv, bias, gamma, beta, out, N);
    }
}

// Round 11
// 176.880 us; speedup vs baseline: 1.4544x; 1.0044x over previous
//
#include <hip/hip_runtime.h>
#include <hip/hip_fp16.h>

#define D 128
#define LN_EPS 1e-5f

// Dtypes (R0-R7 forensics): x,W,b,gamma,beta fp32; edge_index int32; out fp32.
// R8: 234us. R9: 257us (fill2 global atomic-return = 106us). R10: 177.7us —
// counting sort works; fused 55.8us, aux ~122us (C=128 chunk overheads).
// R11: C=32 (quarter the per-chunk fixed costs), chunkoff unroll, fused inner
// loop FULLY unrolled (shfl const-lane -> v_readlane, deeper gather pipelining).

static __device__ __forceinline__ float h2f(unsigned short h) {
    return __half2float(__builtin_bit_cast(__half, h));
}
static __device__ __forceinline__ unsigned short f2h(float f) {
    return __builtin_bit_cast(unsigned short, __float2half_rn(f));
}

// ---- H: per-chunk LDS histogram of dst; also converts x -> packed fp16 ----
__global__ __launch_bounds__(1024) void hist_kernel(const int* __restrict__ dst,
                                                    int* __restrict__ ghist,
                                                    const float* __restrict__ x,
                                                    unsigned int* __restrict__ xh,
                                                    int N, int E, int Ec, int NH) {
    extern __shared__ int hist[];          // N ints (40 KB)
    int c = blockIdx.x;
    for (int i = threadIdx.x; i < N; i += blockDim.x) hist[i] = 0;
    int gs = gridDim.x * blockDim.x;
    for (int i = blockIdx.x * blockDim.x + threadIdx.x; i < NH; i += gs) {
        float2 v = ((const float2*)x)[i];
        xh[i] = (unsigned int)f2h(v.x) | ((unsigned int)f2h(v.y) << 16);
    }
    __syncthreads();
    int lo = c * Ec, hi = min(lo + Ec, E);
    for (int i = lo + threadIdx.x; i < hi; i += blockDim.x)
        atomicAdd(&hist[dst[i]], 1);       // LDS atomic: cheap, no coherence
    __syncthreads();
    for (int i = threadIdx.x; i < N; i += blockDim.x) ghist[c * N + i] = hist[i];
}

// ---- S2: per-node exclusive scan over chunks (in place) -> deg ----
__global__ void chunkoff_kernel(int* __restrict__ ghist, int* __restrict__ deg,
                                int N, int C) {
    int n = blockIdx.x * blockDim.x + threadIdx.x;
    if (n < N) {
        int run = 0;
        #pragma unroll 4
        for (int c = 0; c < C; c++) {      // loads address-independent: pipeline
            int t = ghist[c * N + n];
            ghist[c * N + n] = run;
            run += t;
        }
        deg[n] = run;
    }
}

// ---- scan: exclusive scan of deg -> rowptr (+fill for fallback), dinv ----
__global__ __launch_bounds__(1024) void scan_kernel(const int* __restrict__ deg,
                                                    int* __restrict__ rowptr,
                                                    int* __restrict__ fill,
                                                    float* __restrict__ dinv, int N) {
    __shared__ int s_wsum[16];
    __shared__ int s_woff[16];
    __shared__ int s_carry;
    int t = threadIdx.x;
    int lane = t & 63, w = t >> 6;
    if (t == 0) s_carry = 0;
    __syncthreads();
    for (int base = 0; base < N; base += 1024) {
        int i = base + t;
        int v = (i < N) ? deg[i] : 0;
        int incl = v;
        #pragma unroll
        for (int off = 1; off < 64; off <<= 1) {
            int y = __shfl_up(incl, off);
            if (lane >= off) incl += y;
        }
        if (lane == 63) s_wsum[w] = incl;
        __syncthreads();
        if (t == 0) {
            int run = s_carry;
            #pragma unroll
            for (int k = 0; k < 16; k++) { s_woff[k] = run; run += s_wsum[k]; }
            s_carry = run;
        }
        __syncthreads();
        if (i < N) {
            int rp = s_woff[w] + (incl - v);
            rowptr[i] = rp;
            fill[i] = rp;
            dinv[i] = rsqrtf((float)(v + 1));  // +1 self-loop
        }
    }
    if (t == 0) rowptr[N] = s_carry;
}

// ---- W: per-chunk scatter with LDS cursors; 2B stores, zero global atomics ----
__global__ __launch_bounds__(1024) void scatter_kernel(const int* __restrict__ src,
                                                       const int* __restrict__ dst,
                                                       const int* __restrict__ rowptr,
                                                       const int* __restrict__ goff,
                                                       unsigned short* __restrict__ csr,
                                                       int N, int E, int Ec) {
    extern __shared__ int cnt[];           // N ints
    int c = blockIdx.x;
    for (int i = threadIdx.x; i < N; i += blockDim.x)
        cnt[i] = rowptr[i] + goff[c * N + i];
    __syncthreads();
    int lo = c * Ec, hi = min(lo + Ec, E);
    for (int i = lo + threadIdx.x; i < hi; i += blockDim.x) {
        int d = dst[i];
        int pos = atomicAdd(&cnt[d], 1);   // LDS atomic-return: ~zero contention
        csr[pos] = (unsigned short)src[i];
    }
}

// ---- fused: aggregate (fp16 x, fp32 acc) -> linear (fp16 W in LDS) -> LN ----
__global__ __launch_bounds__(512) void fused_fp16(const unsigned int* __restrict__ xh,
                                                  const float* __restrict__ W,
                                                  const int* __restrict__ rowptr,
                                                  const unsigned short* __restrict__ csr,
                                                  const float* __restrict__ dinv,
                                                  const float* __restrict__ bias,
                                                  const float* __restrict__ gamma,
                                                  const float* __restrict__ beta,
                                                  float* __restrict__ out, int N) {
    __shared__ unsigned int sW2[D * (D / 2)];   // 32 KB -> 4 blocks/CU
    {
        const float2* Wv = (const float2*)W;
        #pragma unroll
        for (int i = 0; i < (D * D / 2) / 512; i++) {
            int idx = threadIdx.x + i * 512;
            float2 wv = Wv[idx];
            sW2[idx] = (unsigned int)f2h(wv.x) | ((unsigned int)f2h(wv.y) << 16);
        }
    }
    __syncthreads();

    int w = threadIdx.x >> 6, lane = threadIdx.x & 63;
    int node = blockIdx.x * 8 + w;
    if (node >= N) return;
    float dn = dinv[node];

    unsigned int xv = xh[node * 64 + lane];
    float a0 = h2f((unsigned short)xv) * dn * dn;
    float a1 = h2f((unsigned short)(xv >> 16)) * dn * dn;

    int start = rowptr[node], end = rowptr[node + 1];
    int base = start;
    for (; base + 64 <= end; base += 64) {
        int s = csr[base + lane];
        float wt = dinv[s] * dn;
        #pragma unroll          // FULL unroll: __shfl(.,k) const-lane -> v_readlane
        for (int k = 0; k < 64; k++) {
            int sk = __shfl(s, k);
            float wk = __shfl(wt, k);
            unsigned int hv = xh[sk * 64 + lane];
            a0 += h2f((unsigned short)hv) * wk;
            a1 += h2f((unsigned short)(hv >> 16)) * wk;
        }
    }
    int rem = end - base;
    if (rem > 0) {
        int s = 0; float wt = 0.f;
        if (lane < rem) { s = csr[base + lane]; wt = dinv[s] * dn; }
        for (int k = 0; k < rem; k++) {
            int sk = __shfl(s, k);
            float wk = __shfl(wt, k);
            unsigned int hv = xh[sk * 64 + lane];
            a0 += h2f((unsigned short)hv) * wk;
            a1 += h2f((unsigned short)(hv >> 16)) * wk;
        }
    }

    int c0 = lane * 2;
    float y0 = bias[c0], y1 = bias[c0 + 1];
    #pragma unroll 8
    for (int k = 0; k < 64; k++) {
        float g0 = __shfl(a0, k);
        float g1 = __shfl(a1, k);
        unsigned int w0 = sW2[(2 * k) * 64 + lane];
        unsigned int w1 = sW2[(2 * k + 1) * 64 + lane];
        y0 += g0 * h2f((unsigned short)w0) + g1 * h2f((unsigned short)w1);
        y1 += g0 * h2f((unsigned short)(w0 >> 16)) + g1 * h2f((unsigned short)(w1 >> 16));
    }

    float sum = y0 + y1, sq = y0 * y0 + y1 * y1;
    #pragma unroll
    for (int off = 32; off > 0; off >>= 1) {
        sum += __shfl_xor(sum, off);
        sq  += __shfl_xor(sq, off);
    }
    float mean = sum * (1.0f / D);
    float var  = sq * (1.0f / D) - mean * mean;
    float inv  = rsqrtf(var + LN_EPS);
    float o0 = (y0 - mean) * inv * gamma[c0] + beta[c0];
    float o1 = (y1 - mean) * inv * gamma[c0 + 1] + beta[c0 + 1];
    *(float2*)(out + (size_t)node * D + c0) = make_float2(o0, o1);
}

// ================= fallback (R8, proven): used only if ws too small =========

__global__ void deg_kernel(const int* __restrict__ dst, int* __restrict__ deg, int E) {
    int e = blockIdx.x * blockDim.x + threadIdx.x;
    if (e < E) atomicAdd(&deg[dst[e]], 1);
}
__global__ void fill_kernel(const int* __restrict__ src, const int* __restrict__ dst,
                            int* __restrict__ fill, unsigned short* __restrict__ csr, int E) {
    int e = blockIdx.x * blockDim.x + threadIdx.x;
    if (e < E) {
        int pos = atomicAdd(&fill[dst[e]], 1);
        csr[pos] = (unsigned short)src[e];
    }
}
__global__ __launch_bounds__(512) void fused_fp32(const float* __restrict__ x,
                                                  const float* __restrict__ W,
                                                  const int* __restrict__ rowptr,
                                                  const unsigned short* __restrict__ csr,
                                                  const float* __restrict__ dinv,
                                                  const float* __restrict__ bias,
                                                  const float* __restrict__ gamma,
                                                  const float* __restrict__ beta,
                                                  float* __restrict__ out, int N) {
    __shared__ float sW[D * D];
    {
        const float4* Wv = (const float4*)W;
        float4* sWv = (float4*)sW;
        #pragma unroll
        for (int i = 0; i < (D * D / 4) / 512; i++)
            sWv[threadIdx.x + i * 512] = Wv[threadIdx.x + i * 512];
    }
    __syncthreads();
    int w = threadIdx.x >> 6, lane = threadIdx.x & 63;
    int node = blockIdx.x * 8 + w;
    if (node >= N) return;
    float dn = dinv[node];
    int c0 = lane * 2;
    float2 xv = *(const float2*)(x + (size_t)node * D + c0);
    float a0 = xv.x * dn * dn, a1 = xv.y * dn * dn;
    int start = rowptr[node], end = rowptr[node + 1];
    int base = start;
    for (; base + 64 <= end; base += 64) {
        int s = csr[base + lane];
        float wt = dinv[s] * dn;
        #pragma unroll 8
        for (int k = 0; k < 64; k++) {
            int sk = __shfl(s, k);
            float wk = __shfl(wt, k);
            float2 xs = *(const float2*)(x + (size_t)sk * D + c0);
            a0 += xs.x * wk; a1 += xs.y * wk;
        }
    }
    int rem = end - base;
    if (rem > 0) {
        int s = 0; float wt = 0.f;
        if (lane < rem) { s = csr[base + lane]; wt = dinv[s] * dn; }
        for (int k = 0; k < rem; k++) {
            int sk = __shfl(s, k);
            float wk = __shfl(wt, k);
            float2 xs = *(const float2*)(x + (size_t)sk * D + c0);
            a0 += xs.x * wk; a1 += xs.y * wk;
        }
    }
    float y0 = bias[c0], y1 = bias[c0 + 1];
    #pragma unroll 8
    for (int k = 0; k < 64; k++) {
        float g0 = __shfl(a0, k);
        float g1 = __shfl(a1, k);
        float2 w0 = *(const float2*)(sW + (2 * k) * D + c0);
        float2 w1 = *(const float2*)(sW + (2 * k + 1) * D + c0);
        y0 += g0 * w0.x + g1 * w1.x;
        y1 += g0 * w0.y + g1 * w1.y;
    }
    float sum = y0 + y1, sq = y0 * y0 + y1 * y1;
    #pragma unroll
    for (int off = 32; off > 0; off >>= 1) {
        sum += __shfl_xor(sum, off);
        sq  += __shfl_xor(sq, off);
    }
    float mean = sum * (1.0f / D);
    float var  = sq * (1.0f / D) - mean * mean;
    float inv  = rsqrtf(var + LN_EPS);
    float o0 = (y0 - mean) * inv * gamma[c0] + beta[c0];
    float o1 = (y1 - mean) * inv * gamma[c0 + 1] + beta[c0 + 1];
    *(float2*)(out + (size_t)node * D + c0) = make_float2(o0, o1);
}

extern "C" void kernel_launch(void* const* d_in, const int* in_sizes, int n_in,
                              void* d_out, int out_size, void* d_ws, size_t ws_size,
                              hipStream_t stream) {
    const float* x     = (const float*)d_in[0];
    const int*   ei    = (const int*)d_in[1];
    const float* W     = (const float*)d_in[2];
    const float* bias  = (const float*)d_in[3];
    const float* gamma = (const float*)d_in[4];
    const float* beta  = (const float*)d_in[5];
    float*       out   = (float*)d_out;

    int N = in_sizes[0] / D;
    int E = in_sizes[1] / 2;
    const int* src = ei;
    const int* dst = ei + E;

    char* ws = (char*)d_ws;
    size_t off = 0;
    auto carve = [&](size_t bytes) { size_t p = off; off = (off + bytes + 15) & ~15UL; return (void*)(ws + p); };
    int*            deg    = (int*)           carve((size_t)N * 4);
    int*            rowptr = (int*)           carve((size_t)(N + 1) * 4);
    int*            fill   = (int*)           carve((size_t)N * 4);
    float*          dinv   = (float*)         carve((size_t)N * 4);
    unsigned short* csr    = (unsigned short*)carve((size_t)E * 2);
    unsigned short* xhbuf  = (unsigned short*)carve((size_t)N * D * 2);
    size_t fixed_end = off;

    // chunks for the atomic-free counting sort: each needs N*4 bytes of ghist.
    // C=32 balances chunk fixed costs (3x 40KB traffic + LDS zero per chunk)
    // against per-chunk LDS-cursor contention (~2 edges/node/chunk).
    int C = 0;
    if (ws_size > fixed_end + 16) {
        size_t avail = ws_size - fixed_end - 16;
        size_t cmax = avail / ((size_t)N * 4);
        C = (int)((cmax > 32) ? 32 : cmax);
    }

    if (C >= 8) {
        int* ghist = (int*)carve((size_t)C * N * 4);
        unsigned int* xh = (unsigned int*)xhbuf;
        int Ec = (E + C - 1) / C;
        int NH = N * (D / 2);
        size_t lds = (size_t)N * 4;
        hist_kernel<<<C, 1024, lds, stream>>>(dst, ghist, x, xh, N, E, Ec, NH);
        chunkoff_kernel<<<(N + 255) / 256, 256, 0, stream>>>(ghist, deg, N, C);
        scan_kernel<<<1, 1024, 0, stream>>>(deg, rowptr, fill, dinv, N);
        scatter_kernel<<<C, 1024, lds, stream>>>(src, dst, rowptr, ghist, csr, N, E, Ec);
        fused_fp16<<<(N + 7) / 8, 512, 0, stream>>>(xh, W, rowptr, csr, dinv, bias, gamma, beta, out, N);
    } else {
        hipMemsetAsync(deg, 0, (size_t)N * 4, stream);
        deg_kernel<<<(E + 255) / 256, 256, 0, stream>>>(dst, deg, E);
        scan_kernel<<<1, 1024, 0, stream>>>(deg, rowptr, fill, dinv, N);
        fill_kernel<<<(E + 255) / 256, 256, 0, stream>>>(src, dst, fill, csr, E);
        fused_fp32<<<(N + 7) / 8, 512, 0, stream>>>(x, W, rowptr, csr, dinv, bias, gamma, beta, out, N);
    }
}

// Round 12
// 154.374 us; speedup vs baseline: 1.6665x; 1.1458x over previous
//
#include <hip/hip_runtime.h>
#include <hip/hip_fp16.h>

#define D 128
#define LN_EPS 1e-5f

// Dtypes (R0-R7 forensics): x,W,b,gamma,beta fp32; edge_index int32; out fp32.
// R8: 234us. R9: 257us (global atomic fill = 106us). R10: 177.7us (fused 55.8,
// aux ~122). R11: 176.9 — full-unroll REGRESSED fused (62.5us, VGPR 52, occ 25%);
// C=32 helped aux (~114). R12: unroll 8 restored; W read as fp16 from global
// (L1-resident, no LDS/barrier in fused -> more waves for gather latency);
// convert pass spread over 256 blocks; C=64.

static __device__ __forceinline__ float h2f(unsigned short h) {
    return __half2float(__builtin_bit_cast(__half, h));
}
static __device__ __forceinline__ unsigned short f2h(float f) {
    return __builtin_bit_cast(unsigned short, __float2half_rn(f));
}

// ---- H: blocks 0..C-1 build per-chunk LDS histogram of dst; ALL blocks
// grid-stride convert x and W to packed fp16 ----
__global__ __launch_bounds__(1024) void hist_kernel(const int* __restrict__ dst,
                                                    int* __restrict__ ghist,
                                                    const float* __restrict__ x,
                                                    unsigned int* __restrict__ xh,
                                                    const float* __restrict__ W,
                                                    unsigned int* __restrict__ Wh,
                                                    int N, int E, int Ec, int NH, int NW,
                                                    int C) {
    extern __shared__ int hist[];          // N ints (40 KB)
    int c = blockIdx.x;
    bool is_hist = (c < C);
    if (is_hist)
        for (int i = threadIdx.x; i < N; i += blockDim.x) hist[i] = 0;
    // convert: domain = NH x-words then NW W-words, across the whole grid
    int gs = gridDim.x * blockDim.x;
    int tot = NH + NW;
    for (int i = blockIdx.x * blockDim.x + threadIdx.x; i < tot; i += gs) {
        if (i < NH) {
            float2 v = ((const float2*)x)[i];
            xh[i] = (unsigned int)f2h(v.x) | ((unsigned int)f2h(v.y) << 16);
        } else {
            float2 v = ((const float2*)W)[i - NH];
            Wh[i - NH] = (unsigned int)f2h(v.x) | ((unsigned int)f2h(v.y) << 16);
        }
    }
    if (!is_hist) return;
    __syncthreads();
    int lo = c * Ec, hi = min(lo + Ec, E);
    for (int i = lo + threadIdx.x; i < hi; i += blockDim.x)
        atomicAdd(&hist[dst[i]], 1);       // LDS atomic: cheap, no coherence
    __syncthreads();
    for (int i = threadIdx.x; i < N; i += blockDim.x) ghist[c * N + i] = hist[i];
}

// ---- S2: per-node exclusive scan over chunks (in place) -> deg ----
__global__ void chunkoff_kernel(int* __restrict__ ghist, int* __restrict__ deg,
                                int N, int C) {
    int n = blockIdx.x * blockDim.x + threadIdx.x;
    if (n < N) {
        int run = 0;
        #pragma unroll 4
        for (int c = 0; c < C; c++) {
            int t = ghist[c * N + n];
            ghist[c * N + n] = run;
            run += t;
        }
        deg[n] = run;
    }
}

// ---- scan: exclusive scan of deg -> rowptr (+fill for fallback), dinv ----
__global__ __launch_bounds__(1024) void scan_kernel(const int* __restrict__ deg,
                                                    int* __restrict__ rowptr,
                                                    int* __restrict__ fill,
                                                    float* __restrict__ dinv, int N) {
    __shared__ int s_wsum[16];
    __shared__ int s_woff[16];
    __shared__ int s_carry;
    int t = threadIdx.x;
    int lane = t & 63, w = t >> 6;
    if (t == 0) s_carry = 0;
    __syncthreads();
    for (int base = 0; base < N; base += 1024) {
        int i = base + t;
        int v = (i < N) ? deg[i] : 0;
        int incl = v;
        #pragma unroll
        for (int off = 1; off < 64; off <<= 1) {
            int y = __shfl_up(incl, off);
            if (lane >= off) incl += y;
        }
        if (lane == 63) s_wsum[w] = incl;
        __syncthreads();
        if (t == 0) {
            int run = s_carry;
            #pragma unroll
            for (int k = 0; k < 16; k++) { s_woff[k] = run; run += s_wsum[k]; }
            s_carry = run;
        }
        __syncthreads();
        if (i < N) {
            int rp = s_woff[w] + (incl - v);
            rowptr[i] = rp;
            fill[i] = rp;
            dinv[i] = rsqrtf((float)(v + 1));  // +1 self-loop
        }
    }
    if (t == 0) rowptr[N] = s_carry;
}

// ---- W: per-chunk scatter with LDS cursors; 2B stores, zero global atomics ----
__global__ __launch_bounds__(1024) void scatter_kernel(const int* __restrict__ src,
                                                       const int* __restrict__ dst,
                                                       const int* __restrict__ rowptr,
                                                       const int* __restrict__ goff,
                                                       unsigned short* __restrict__ csr,
                                                       int N, int E, int Ec) {
    extern __shared__ int cnt[];           // N ints
    int c = blockIdx.x;
    for (int i = threadIdx.x; i < N; i += blockDim.x)
        cnt[i] = rowptr[i] + goff[c * N + i];
    __syncthreads();
    int lo = c * Ec, hi = min(lo + Ec, E);
    for (int i = lo + threadIdx.x; i < hi; i += blockDim.x) {
        int d = dst[i];
        int pos = atomicAdd(&cnt[d], 1);   // LDS atomic-return: ~zero contention
        csr[pos] = (unsigned short)src[i];
    }
}

// ---- fused: aggregate (fp16 x, fp32 acc) -> linear (fp16 W from global/L1) -> LN
// No LDS, no barrier: max wave supply for gather-latency hiding.
__global__ __launch_bounds__(512) void fused_fp16(const unsigned int* __restrict__ xh,
                                                  const unsigned int* __restrict__ Wh,
                                                  const int* __restrict__ rowptr,
                                                  const unsigned short* __restrict__ csr,
                                                  const float* __restrict__ dinv,
                                                  const float* __restrict__ bias,
                                                  const float* __restrict__ gamma,
                                                  const float* __restrict__ beta,
                                                  float* __restrict__ out, int N) {
    int w = threadIdx.x >> 6, lane = threadIdx.x & 63;
    int node = blockIdx.x * 8 + w;
    if (node >= N) return;
    float dn = dinv[node];

    unsigned int xv = xh[node * 64 + lane];
    float a0 = h2f((unsigned short)xv) * dn * dn;
    float a1 = h2f((unsigned short)(xv >> 16)) * dn * dn;

    int start = rowptr[node], end = rowptr[node + 1];
    int base = start;
    for (; base + 64 <= end; base += 64) {
        int s = csr[base + lane];
        float wt = dinv[s] * dn;
        #pragma unroll 8
        for (int k = 0; k < 64; k++) {
            int sk = __shfl(s, k);
            float wk = __shfl(wt, k);
            unsigned int hv = xh[sk * 64 + lane];
            a0 += h2f((unsigned short)hv) * wk;
            a1 += h2f((unsigned short)(hv >> 16)) * wk;
        }
    }
    int rem = end - base;
    if (rem > 0) {
        int s = 0; float wt = 0.f;
        if (lane < rem) { s = csr[base + lane]; wt = dinv[s] * dn; }
        for (int k = 0; k < rem; k++) {
            int sk = __shfl(s, k);
            float wk = __shfl(wt, k);
            unsigned int hv = xh[sk * 64 + lane];
            a0 += h2f((unsigned short)hv) * wk;
            a1 += h2f((unsigned short)(hv >> 16)) * wk;
        }
    }

    // linear: Wh is 32 KB total -> L1-resident; same addresses across waves
    int c0 = lane * 2;
    float y0 = bias[c0], y1 = bias[c0 + 1];
    #pragma unroll 8
    for (int k = 0; k < 64; k++) {
        float g0 = __shfl(a0, k);
        float g1 = __shfl(a1, k);
        unsigned int w0 = Wh[(2 * k) * 64 + lane];
        unsigned int w1 = Wh[(2 * k + 1) * 64 + lane];
        y0 += g0 * h2f((unsigned short)w0) + g1 * h2f((unsigned short)w1);
        y1 += g0 * h2f((unsigned short)(w0 >> 16)) + g1 * h2f((unsigned short)(w1 >> 16));
    }

    float sum = y0 + y1, sq = y0 * y0 + y1 * y1;
    #pragma unroll
    for (int off = 32; off > 0; off >>= 1) {
        sum += __shfl_xor(sum, off);
        sq  += __shfl_xor(sq, off);
    }
    float mean = sum * (1.0f / D);
    float var  = sq * (1.0f / D) - mean * mean;
    float inv  = rsqrtf(var + LN_EPS);
    float o0 = (y0 - mean) * inv * gamma[c0] + beta[c0];
    float o1 = (y1 - mean) * inv * gamma[c0 + 1] + beta[c0 + 1];
    *(float2*)(out + (size_t)node * D + c0) = make_float2(o0, o1);
}

// ================= fallback (R8, proven): used only if ws too small =========

__global__ void deg_kernel(const int* __restrict__ dst, int* __restrict__ deg, int E) {
    int e = blockIdx.x * blockDim.x + threadIdx.x;
    if (e < E) atomicAdd(&deg[dst[e]], 1);
}
__global__ void fill_kernel(const int* __restrict__ src, const int* __restrict__ dst,
                            int* __restrict__ fill, unsigned short* __restrict__ csr, int E) {
    int e = blockIdx.x * blockDim.x + threadIdx.x;
    if (e < E) {
        int pos = atomicAdd(&fill[dst[e]], 1);
        csr[pos] = (unsigned short)src[e];
    }
}
__global__ __launch_bounds__(512) void fused_fp32(const float* __restrict__ x,
                                                  const float* __restrict__ W,
                                                  const int* __restrict__ rowptr,
                                                  const unsigned short* __restrict__ csr,
                                                  const float* __restrict__ dinv,
                                                  const float* __restrict__ bias,
                                                  const float* __restrict__ gamma,
                                                  const float* __restrict__ beta,
                                                  float* __restrict__ out, int N) {
    __shared__ float sW[D * D];
    {
        const float4* Wv = (const float4*)W;
        float4* sWv = (float4*)sW;
        #pragma unroll
        for (int i = 0; i < (D * D / 4) / 512; i++)
            sWv[threadIdx.x + i * 512] = Wv[threadIdx.x + i * 512];
    }
    __syncthreads();
    int w = threadIdx.x >> 6, lane = threadIdx.x & 63;
    int node = blockIdx.x * 8 + w;
    if (node >= N) return;
    float dn = dinv[node];
    int c0 = lane * 2;
    float2 xv = *(const float2*)(x + (size_t)node * D + c0);
    float a0 = xv.x * dn * dn, a1 = xv.y * dn * dn;
    int start = rowptr[node], end = rowptr[node + 1];
    int base = start;
    for (; base + 64 <= end; base += 64) {
        int s = csr[base + lane];
        float wt = dinv[s] * dn;
        #pragma unroll 8
        for (int k = 0; k < 64; k++) {
            int sk = __shfl(s, k);
            float wk = __shfl(wt, k);
            float2 xs = *(const float2*)(x + (size_t)sk * D + c0);
            a0 += xs.x * wk; a1 += xs.y * wk;
        }
    }
    int rem = end - base;
    if (rem > 0) {
        int s = 0; float wt = 0.f;
        if (lane < rem) { s = csr[base + lane]; wt = dinv[s] * dn; }
        for (int k = 0; k < rem; k++) {
            int sk = __shfl(s, k);
            float wk = __shfl(wt, k);
            float2 xs = *(const float2*)(x + (size_t)sk * D + c0);
            a0 += xs.x * wk; a1 += xs.y * wk;
        }
    }
    float y0 = bias[c0], y1 = bias[c0 + 1];
    #pragma unroll 8
    for (int k = 0; k < 64; k++) {
        float g0 = __shfl(a0, k);
        float g1 = __shfl(a1, k);
        float2 w0 = *(const float2*)(sW + (2 * k) * D + c0);
        float2 w1 = *(const float2*)(sW + (2 * k + 1) * D + c0);
        y0 += g0 * w0.x + g1 * w1.x;
        y1 += g0 * w0.y + g1 * w1.y;
    }
    float sum = y0 + y1, sq = y0 * y0 + y1 * y1;
    #pragma unroll
    for (int off = 32; off > 0; off >>= 1) {
        sum += __shfl_xor(sum, off);
        sq  += __shfl_xor(sq, off);
    }
    float mean = sum * (1.0f / D);
    float var  = sq * (1.0f / D) - mean * mean;
    float inv  = rsqrtf(var + LN_EPS);
    float o0 = (y0 - mean) * inv * gamma[c0] + beta[c0];
    float o1 = (y1 - mean) * inv * gamma[c0 + 1] + beta[c0 + 1];
    *(float2*)(out + (size_t)node * D + c0) = make_float2(o0, o1);
}

extern "C" void kernel_launch(void* const* d_in, const int* in_sizes, int n_in,
                              void* d_out, int out_size, void* d_ws, size_t ws_size,
                              hipStream_t stream) {
    const float* x     = (const float*)d_in[0];
    const int*   ei    = (const int*)d_in[1];
    const float* W     = (const float*)d_in[2];
    const float* bias  = (const float*)d_in[3];
    const float* gamma = (const float*)d_in[4];
    const float* beta  = (const float*)d_in[5];
    float*       out   = (float*)d_out;

    int N = in_sizes[0] / D;
    int E = in_sizes[1] / 2;
    const int* src = ei;
    const int* dst = ei + E;

    char* ws = (char*)d_ws;
    size_t off = 0;
    auto carve = [&](size_t bytes) { size_t p = off; off = (off + bytes + 15) & ~15UL; return (void*)(ws + p); };
    int*            deg    = (int*)           carve((size_t)N * 4);
    int*            rowptr = (int*)           carve((size_t)(N + 1) * 4);
    int*            fill   = (int*)           carve((size_t)N * 4);
    float*          dinv   = (float*)         carve((size_t)N * 4);
    unsigned short* csr    = (unsigned short*)carve((size_t)E * 2);
    unsigned short* xhbuf  = (unsigned short*)carve((size_t)N * D * 2);
    unsigned int*   Wh     = (unsigned int*)  carve((size_t)D * D / 2 * 4);
    size_t fixed_end = off;

    // chunks for the atomic-free counting sort: each needs N*4 bytes of ghist.
    int C = 0;
    if (ws_size > fixed_end + 16) {
        size_t avail = ws_size - fixed_end - 16;
        size_t cmax = avail / ((size_t)N * 4);
        C = (int)((cmax > 64) ? 64 : cmax);
    }

    if (C >= 8) {
        int* ghist = (int*)carve((size_t)C * N * 4);
        unsigned int* xh = (unsigned int*)xhbuf;
        int Ec = (E + C - 1) / C;
        int NH = N * (D / 2);
        int NW = D * D / 2;
        size_t lds = (size_t)N * 4;
        int hist_grid = (256 > C) ? 256 : C;   // extra blocks help the convert
        hist_kernel<<<hist_grid, 1024, lds, stream>>>(dst, ghist, x, xh, W, Wh,
                                                      N, E, Ec, NH, NW, C);
        chunkoff_kernel<<<(N + 255) / 256, 256, 0, stream>>>(ghist, deg, N, C);
        scan_kernel<<<1, 1024, 0, stream>>>(deg, rowptr, fill, dinv, N);
        scatter_kernel<<<C, 1024, lds, stream>>>(src, dst, rowptr, ghist, csr, N, E, Ec);
        fused_fp16<<<(N + 7) / 8, 512, 0, stream>>>(xh, Wh, rowptr, csr, dinv, bias, gamma, beta, out, N);
    } else {
        hipMemsetAsync(deg, 0, (size_t)N * 4, stream);
        deg_kernel<<<(E + 255) / 256, 256, 0, stream>>>(dst, deg, E);
        scan_kernel<<<1, 1024, 0, stream>>>(deg, rowptr, fill, dinv, N);
        fill_kernel<<<(E + 255) / 256, 256, 0, stream>>>(src, dst, fill, csr, E);
        fused_fp32<<<(N + 7) / 8, 512, 0, stream>>>(x, W, rowptr, csr, dinv, bias, gamma, beta, out, N);
    }
}